// Round 9
// baseline (179.287 us; speedup 1.0000x reference)
//
#include <hip/hip_runtime.h>
#include <math.h>

#define NE 64
#define ND 512
#define NH 1024
#define NT 256
#define NC 8   // token slots per fc1 weight pass (pad amount in build_group)

// ws layout: done[64] ints (256B block) | h[NT*NH] floats

__device__ __forceinline__ int build_group(const int* __restrict__ idx, int e,
                                           int* tok_lds, int* wsum) {
    const int t = threadIdx.x, wave = t >> 6, lane = t & 63;
    const bool m = (idx[t] == e);
    const unsigned long long mask = __ballot(m);
    if (lane == 0) wsum[wave] = __popcll(mask);
    __syncthreads();
    int before = 0;
#pragma unroll
    for (int w = 0; w < 3; ++w) before += (w < wave) ? wsum[w] : 0;
    const int nt = wsum[0] + wsum[1] + wsum[2] + wsum[3];
    if (m) {
        int pos = before + __popcll(mask & ((1ull << lane) - 1ull));
        tok_lds[pos] = t;
    }
    __syncthreads();
    // pad so fragment loads are unconditional (dupes of token 0; stores stay
    // guarded by nt, so pad results are discarded)
    if (nt > 0 && t >= nt && t < nt + NC) tok_lds[t] = tok_lds[0];
    __syncthreads();
    return nt;
}

// Fused butterfly over 8 accumulators: 10 shuffles, depth 6, for 8 full
// 64-lane reductions. On exit lanes 0..7 hold the sum for token bitrev3(lane).
__device__ __forceinline__ float fused_reduce8_64(float v[NC], int lane) {
#pragma unroll
    for (int i = 0; i < 4; ++i) {
        float lo = v[i], hi = v[i + 4];
        float send = (lane & 1) ? lo : hi;
        float recv = __shfl_xor(send, 1);
        v[i] = ((lane & 1) ? hi : lo) + recv;
    }
#pragma unroll
    for (int i = 0; i < 2; ++i) {
        float lo = v[i], hi = v[i + 2];
        float send = (lane & 2) ? lo : hi;
        float recv = __shfl_xor(send, 2);
        v[i] = ((lane & 2) ? hi : lo) + recv;
    }
    {
        float lo = v[0], hi = v[1];
        float send = (lane & 4) ? lo : hi;
        float recv = __shfl_xor(send, 4);
        v[0] = ((lane & 4) ? hi : lo) + recv;
    }
    v[0] += __shfl_xor(v[0], 8);
    v[0] += __shfl_xor(v[0], 16);
    v[0] += __shfl_xor(v[0], 32);
    return v[0];
}

// Fused butterfly over 4 accumulators -> full 64-lane sums.
// On exit lane l holds the sum for token t = 2*(l&1) + ((l>>1)&1).
__device__ __forceinline__ float fused_reduce4_64(float v[4], int lane) {
#pragma unroll
    for (int i = 0; i < 2; ++i) {
        float lo = v[i], hi = v[i + 2];
        float send = (lane & 1) ? lo : hi;
        float recv = __shfl_xor(send, 1);
        v[i] = ((lane & 1) ? hi : lo) + recv;
    }
    {
        float lo = v[0], hi = v[1];
        float send = (lane & 2) ? lo : hi;
        float recv = __shfl_xor(send, 2);
        v[0] = ((lane & 2) ? hi : lo) + recv;
    }
    v[0] += __shfl_xor(v[0], 4);
    v[0] += __shfl_xor(v[0], 8);
    v[0] += __shfl_xor(v[0], 16);
    v[0] += __shfl_xor(v[0], 32);
    return v[0];
}

// Single plain-launch kernel, grid = 512 = 2 blocks/CU. __launch_bounds__
// (256,2) guarantees >=2 waves/EU (<=256 VGPR; actual ~110 -> capacity
// >=4 blocks/CU, 2x margin) so ALL 512 blocks are co-resident -> the
// per-expert spin never waits on an undispatched block.
// Block (e, c in [0,8)): fc1 for 128 H-rows -> release done[e]++ -> spin
// till done[e]==8 (own expert only; siblings run concurrently) -> fc2 for
// 64 D-rows. No grid drain, one launch, one build_group.
__global__ __launch_bounds__(256, 2) void moe_kernel(
    const float* __restrict__ x, const float* __restrict__ w1,
    const float* __restrict__ w2, const int* __restrict__ idx,
    float* __restrict__ h, int* __restrict__ done, float* __restrict__ out) {
    __shared__ int tok_lds[NT + NC];
    __shared__ int wsum[4];
    const int b = blockIdx.x;
    const int e = b >> 3;
    const int c = b & 7;
    const int tid = threadIdx.x, wave = tid >> 6, lane = tid & 63;
    const int nt = build_group(idx, e, tok_lds, wsum);
    if (nt == 0) return;   // siblings share nt: nobody waits on empty experts

    // ------------- Phase 1: fc1 (128 H-rows: 4 waves x 32 rows) -----------
    {
        const float* w1e = w1 + (size_t)e * NH * ND;
        const int jw = c * 128 + wave * 32;
        for (int base = 0; base < nt; base += NC) {
            float4 xa[NC], xb[NC];
#pragma unroll
            for (int t = 0; t < NC; ++t) {
                const float* xr = x + (size_t)tok_lds[base + t] * ND;
                xa[t] = *(const float4*)(xr + lane * 4);
                xb[t] = *(const float4*)(xr + 256 + lane * 4);
            }
#pragma unroll 4
            for (int r = 0; r < 32; ++r) {
                const float* wr = w1e + (size_t)(jw + r) * ND;
                const float4 wa = *(const float4*)(wr + lane * 4);
                const float4 wb = *(const float4*)(wr + 256 + lane * 4);
                float acc[NC];
#pragma unroll
                for (int t = 0; t < NC; ++t) {
                    acc[t] = wa.x * xa[t].x + wa.y * xa[t].y + wa.z * xa[t].z + wa.w * xa[t].w
                           + wb.x * xb[t].x + wb.y * xb[t].y + wb.z * xb[t].z + wb.w * xb[t].w;
                }
                float p = fused_reduce8_64(acc, lane);
                if (lane < NC) {
                    int t = ((lane & 1) << 2) | (lane & 2) | ((lane >> 2) & 1);
                    if (base + t < nt) {
                        int tk = tok_lds[base + t];
                        float s = p / (1.0f + __expf(-p));
                        h[(size_t)tk * NH + (jw + r)] = s;
                    }
                }
            }
        }
    }

    // ------------- Handoff: release h, wait for own expert ----------------
    __syncthreads();   // all h-stores in block issued & drained (vmcnt before barrier)
    if (tid == 0) {
        __hip_atomic_fetch_add(&done[e], 1, __ATOMIC_RELEASE,
                               __HIP_MEMORY_SCOPE_AGENT);
        int spins = 0;
        while (__hip_atomic_load(&done[e], __ATOMIC_ACQUIRE,
                                 __HIP_MEMORY_SCOPE_AGENT) < 8) {
            __builtin_amdgcn_s_sleep(8);
            if (++spins > (1 << 22)) break;   // turn a would-be hang into a
                                              // detectable wrong answer
        }
    }
    __syncthreads();
    __threadfence();   // agent-scope acquire for all threads before h reads

    // ------------- Phase 2: fc2 (64 D-rows: 4 waves x 16 rows) ------------
    {
        const float* w2e = w2 + (size_t)e * ND * NH;
        const int d0 = c * 64 + wave * 16;
        for (int base = 0; base < nt; base += 4) {
            float4 hb0[4], hb1[4], hb2[4], hb3[4];
#pragma unroll
            for (int t = 0; t < 4; ++t) {
                const float* hr = h + (size_t)tok_lds[base + t] * NH;
                hb0[t] = *(const float4*)(hr + lane * 4);
                hb1[t] = *(const float4*)(hr + 256 + lane * 4);
                hb2[t] = *(const float4*)(hr + 512 + lane * 4);
                hb3[t] = *(const float4*)(hr + 768 + lane * 4);
            }
#pragma unroll 4
            for (int r = 0; r < 16; ++r) {
                const float* wr = w2e + (size_t)(d0 + r) * NH;
                const float4 w0 = *(const float4*)(wr + lane * 4);
                const float4 w1v = *(const float4*)(wr + 256 + lane * 4);
                const float4 w2v = *(const float4*)(wr + 512 + lane * 4);
                const float4 w3v = *(const float4*)(wr + 768 + lane * 4);
                float acc[4];
#pragma unroll
                for (int t = 0; t < 4; ++t) {
                    acc[t] = w0.x * hb0[t].x + w0.y * hb0[t].y + w0.z * hb0[t].z + w0.w * hb0[t].w
                           + w1v.x * hb1[t].x + w1v.y * hb1[t].y + w1v.z * hb1[t].z + w1v.w * hb1[t].w
                           + w2v.x * hb2[t].x + w2v.y * hb2[t].y + w2v.z * hb2[t].z + w2v.w * hb2[t].w
                           + w3v.x * hb3[t].x + w3v.y * hb3[t].y + w3v.z * hb3[t].z + w3v.w * hb3[t].w;
                }
                float p = fused_reduce4_64(acc, lane);
                if (lane < 4) {
                    int t = ((lane & 1) << 1) | ((lane >> 1) & 1);
                    int slot = base + t;
                    if (slot < nt) {
                        int tk = tok_lds[slot];
                        out[(size_t)tk * ND + (d0 + r)] = p;
                    }
                }
            }
        }
    }
}

extern "C" void kernel_launch(void* const* d_in, const int* in_sizes, int n_in,
                              void* d_out, int out_size, void* d_ws, size_t ws_size,
                              hipStream_t stream) {
    const float* x    = (const float*)d_in[0];
    const int*   eidx = (const int*)d_in[1];
    const float* fc1w = (const float*)d_in[2];
    const float* fc2w = (const float*)d_in[3];
    float* out  = (float*)d_out;
    int*   done = (int*)d_ws;
    float* h    = (float*)((char*)d_ws + 256);

    hipMemsetAsync(done, 0, 256, stream);
    moe_kernel<<<512, 256, 0, stream>>>(x, fc1w, fc2w, eidx, h, done, out);
}

// Round 10
// 66.496 us; speedup vs baseline: 2.6962x; 2.6962x over previous
//
#include <hip/hip_runtime.h>
#include <math.h>

#define NE 64
#define ND 512
#define NH 1024
#define NT 256
#define NC 8   // fc1 token chunk; also pad amount in build_group
#define NC2 4  // fc2 token chunk

// ws layout: h[NT*NH] floats

__device__ __forceinline__ int build_group(const int* __restrict__ idx, int e,
                                           int* tok_lds, int* wsum) {
    const int t = threadIdx.x, wave = t >> 6, lane = t & 63;
    const bool m = (idx[t] == e);
    const unsigned long long mask = __ballot(m);
    if (lane == 0) wsum[wave] = __popcll(mask);
    __syncthreads();
    int before = 0;
#pragma unroll
    for (int w = 0; w < 3; ++w) before += (w < wave) ? wsum[w] : 0;
    const int nt = wsum[0] + wsum[1] + wsum[2] + wsum[3];
    if (m) {
        int pos = before + __popcll(mask & ((1ull << lane) - 1ull));
        tok_lds[pos] = t;
    }
    __syncthreads();
    // pad so staging loads are unconditional (dupes of token 0; stores stay
    // guarded by nt, so pad results are discarded)
    if (nt > 0 && t >= nt && t < nt + NC) tok_lds[t] = tok_lds[0];
    __syncthreads();
    return nt;
}

// Fused butterfly over 8 accumulators: 10 shuffles, depth 6, for 8 full
// 64-lane reductions. On exit lanes 0..7 hold the sum for token bitrev3(lane).
__device__ __forceinline__ float fused_reduce8_64(float v[NC], int lane) {
#pragma unroll
    for (int i = 0; i < 4; ++i) {
        float lo = v[i], hi = v[i + 4];
        float send = (lane & 1) ? lo : hi;
        float recv = __shfl_xor(send, 1);
        v[i] = ((lane & 1) ? hi : lo) + recv;
    }
#pragma unroll
    for (int i = 0; i < 2; ++i) {
        float lo = v[i], hi = v[i + 2];
        float send = (lane & 2) ? lo : hi;
        float recv = __shfl_xor(send, 2);
        v[i] = ((lane & 2) ? hi : lo) + recv;
    }
    {
        float lo = v[0], hi = v[1];
        float send = (lane & 4) ? lo : hi;
        float recv = __shfl_xor(send, 4);
        v[0] = ((lane & 4) ? hi : lo) + recv;
    }
    v[0] += __shfl_xor(v[0], 8);
    v[0] += __shfl_xor(v[0], 16);
    v[0] += __shfl_xor(v[0], 32);
    return v[0];
}

// Fused butterfly over 4 accumulators -> full 64-lane sums.
// On exit lane l holds the sum for token t = 2*(l&1) + ((l>>1)&1).
__device__ __forceinline__ float fused_reduce4_64(float v[4], int lane) {
#pragma unroll
    for (int i = 0; i < 2; ++i) {
        float lo = v[i], hi = v[i + 2];
        float send = (lane & 1) ? lo : hi;
        float recv = __shfl_xor(send, 1);
        v[i] = ((lane & 1) ? hi : lo) + recv;
    }
    {
        float lo = v[0], hi = v[1];
        float send = (lane & 2) ? lo : hi;
        float recv = __shfl_xor(send, 2);
        v[0] = ((lane & 2) ? hi : lo) + recv;
    }
    v[0] += __shfl_xor(v[0], 4);
    v[0] += __shfl_xor(v[0], 8);
    v[0] += __shfl_xor(v[0], 16);
    v[0] += __shfl_xor(v[0], 32);
    return v[0];
}

// fc1: grid = NE*32; block owns 32 H-rows (4 waves x 8 rows). x for the
// 8-token chunk staged ONCE in LDS (16KB) and shared by all 4 waves ->
// kills the per-row x re-reads from L2 (compiler won't hold 64+ VGPR of
// fragments; it was re-materializing ~1GB of L2 traffic per dispatch).
// Weight lane map: k in [4l,4l+4) and [256+4l,256+4l+4)  (coalesced 1KB).
__global__ __launch_bounds__(256) void fc1_kernel(
    const float* __restrict__ x, const float* __restrict__ w1,
    const int* __restrict__ idx, float* __restrict__ h) {
    __shared__ int tok_lds[NT + NC];
    __shared__ int wsum[4];
    __shared__ float xs[NC][ND];   // 16 KB
    const int e  = blockIdx.x >> 5;
    const int ch = blockIdx.x & 31;
    const int tid = threadIdx.x, wave = tid >> 6, lane = tid & 63;
    const int nt = build_group(idx, e, tok_lds, wsum);
    if (nt == 0) return;
    const float* w1e = w1 + (size_t)e * NH * ND;
    const int jw = ch * 32 + wave * 8;

    for (int base = 0; base < nt; base += NC) {
        __syncthreads();   // protect xs from previous pass readers
        // stage 8 tokens x 512 floats: 1024 float4 over 256 threads (4 iters)
        for (int i = tid; i < NC * (ND / 4); i += 256) {
            int t = i >> 7, k = (i & 127) * 4;
            *(float4*)&xs[t][k] =
                *(const float4*)(x + (size_t)tok_lds[base + t] * ND + k);
        }
        __syncthreads();

#pragma unroll 4
        for (int r = 0; r < 8; ++r) {
            const float* wr = w1e + (size_t)(jw + r) * ND;
            const float4 wa = *(const float4*)(wr + lane * 4);
            const float4 wb = *(const float4*)(wr + 256 + lane * 4);
            float acc[NC];
#pragma unroll
            for (int t = 0; t < NC; ++t) {
                const float4 xa = *(const float4*)&xs[t][lane * 4];
                const float4 xb = *(const float4*)&xs[t][256 + lane * 4];
                acc[t] = wa.x * xa.x + wa.y * xa.y + wa.z * xa.z + wa.w * xa.w
                       + wb.x * xb.x + wb.y * xb.y + wb.z * xb.z + wb.w * xb.w;
            }
            float p = fused_reduce8_64(acc, lane);
            if (lane < NC) {
                int t = ((lane & 1) << 2) | (lane & 2) | ((lane >> 2) & 1);
                if (base + t < nt) {
                    int tk = tok_lds[base + t];
                    float s = p / (1.0f + __expf(-p));
                    h[(size_t)tk * NH + (jw + r)] = s;
                }
            }
        }
    }
}

// fc2: grid = NE*32; block owns 16 D-rows (4 waves x 4 rows), every wave
// processes ALL 4 tokens of the chunk. h staged once in LDS (16KB), shared
// by all waves. Lane covers k in {4l..4l+3} + {0,256,512,768} of NH=1024.
__global__ __launch_bounds__(256) void fc2_kernel(
    const float* __restrict__ h, const float* __restrict__ w2,
    const int* __restrict__ idx, float* __restrict__ out) {
    __shared__ int tok_lds[NT + NC];
    __shared__ int wsum[4];
    __shared__ float hs[NC2][NH];  // 16 KB
    const int e  = blockIdx.x >> 5;
    const int ch = blockIdx.x & 31;
    const int tid = threadIdx.x, wave = tid >> 6, lane = tid & 63;
    const int nt = build_group(idx, e, tok_lds, wsum);
    if (nt == 0) return;
    const float* w2e = w2 + (size_t)e * ND * NH;
    const int d0 = ch * 16 + wave * 4;

    for (int base = 0; base < nt; base += NC2) {
        __syncthreads();   // protect hs from previous pass readers
        // stage 4 tokens x 1024 floats: 1024 float4 over 256 threads (4 iters)
        for (int i = tid; i < NC2 * (NH / 4); i += 256) {
            int t = i >> 8, k = (i & 255) * 4;
            *(float4*)&hs[t][k] =
                *(const float4*)(h + (size_t)tok_lds[base + t] * NH + k);
        }
        __syncthreads();

#pragma unroll
        for (int r = 0; r < 4; ++r) {
            const float* wr = w2e + (size_t)(d0 + r) * NH;
            const float4 w0 = *(const float4*)(wr + lane * 4);
            const float4 w1v = *(const float4*)(wr + 256 + lane * 4);
            const float4 w2v = *(const float4*)(wr + 512 + lane * 4);
            const float4 w3v = *(const float4*)(wr + 768 + lane * 4);
            float acc[NC2];
#pragma unroll
            for (int t = 0; t < NC2; ++t) {
                const float4 h0 = *(const float4*)&hs[t][lane * 4];
                const float4 h1 = *(const float4*)&hs[t][256 + lane * 4];
                const float4 h2 = *(const float4*)&hs[t][512 + lane * 4];
                const float4 h3 = *(const float4*)&hs[t][768 + lane * 4];
                acc[t] = w0.x * h0.x + w0.y * h0.y + w0.z * h0.z + w0.w * h0.w
                       + w1v.x * h1.x + w1v.y * h1.y + w1v.z * h1.z + w1v.w * h1.w
                       + w2v.x * h2.x + w2v.y * h2.y + w2v.z * h2.z + w2v.w * h2.w
                       + w3v.x * h3.x + w3v.y * h3.y + w3v.z * h3.z + w3v.w * h3.w;
            }
            float p = fused_reduce4_64(acc, lane);
            if (lane < NC2) {
                int t = ((lane & 1) << 1) | ((lane >> 1) & 1);
                int slot = base + t;
                if (slot < nt) {
                    int tk = tok_lds[slot];
                    out[(size_t)tk * ND + (d0 + r)] = p;
                }
            }
        }
    }
}

extern "C" void kernel_launch(void* const* d_in, const int* in_sizes, int n_in,
                              void* d_out, int out_size, void* d_ws, size_t ws_size,
                              hipStream_t stream) {
    const float* x    = (const float*)d_in[0];
    const int*   eidx = (const int*)d_in[1];
    const float* fc1w = (const float*)d_in[2];
    const float* fc2w = (const float*)d_in[3];
    float* out = (float*)d_out;
    float* h   = (float*)d_ws;

    fc1_kernel<<<NE * 32, 256, 0, stream>>>(x, fc1w, eidx, h);
    fc2_kernel<<<NE * 32, 256, 0, stream>>>(h, fc2w, eidx, out);
}